// Round 1
// baseline (963.553 us; speedup 1.0000x reference)
//
#include <hip/hip_runtime.h>

// ---------------------------------------------------------------------------
// Tiled GEMM: C[r][n][MPR] = A[n][64] * B[r][64][MPR] (+ bias), optional ReLU
// on A at load. 64 nodes x 64 m-columns per block, 256 threads, 4x4 register
// tile per thread. As padded to stride 68 (16B-aligned rows, conflict-light).
// ---------------------------------------------------------------------------
template<int MPR>
__global__ __launch_bounds__(256) void gemm_rel(
    const float* __restrict__ A, const float* __restrict__ B,
    const float* __restrict__ bias, float* __restrict__ C,
    int N, int Mtotal, int relu)
{
    __shared__ float As[64][68];   // [d][n], padded
    __shared__ float Bs[64][64];   // [d][m_local]
    const int tid = threadIdx.x;
    const int n0 = blockIdx.x * 64;
    const int mb = blockIdx.y * 64;

    // Stage A tile, transposed: lanes read consecutive d (coalesced 256B),
    // write As[d][n] with stride-68 rows.
    #pragma unroll
    for (int idx = tid; idx < 4096; idx += 256) {
        int n = idx >> 6, d = idx & 63;
        int gn = n0 + n;
        float v = 0.f;
        if (gn < N) v = A[(size_t)gn * 64 + d];
        if (relu) v = fmaxf(v, 0.f);
        As[d][n] = v;
    }
    // Stage B tile: m local contiguous per row -> conflict-free.
    #pragma unroll
    for (int idx = tid; idx < 4096; idx += 256) {
        int d = idx >> 6, ml = idx & 63;
        int gm = mb + ml;
        float v = 0.f;
        if (gm < Mtotal) {
            int r = gm / MPR, o = gm % MPR;   // compile-time shifts (MPR=64/32)
            v = B[((size_t)r * 64 + d) * MPR + o];
        }
        Bs[d][ml] = v;
    }
    __syncthreads();

    const int tx = tid & 15, ty = tid >> 4;   // tx -> nodes, ty -> m
    float acc[4][4] = {};
    #pragma unroll 8
    for (int d = 0; d < 64; ++d) {
        float4 a4 = *(const float4*)&As[d][tx * 4];
        float4 b4 = *(const float4*)&Bs[d][ty * 4];
        float a[4] = {a4.x, a4.y, a4.z, a4.w};
        float b[4] = {b4.x, b4.y, b4.z, b4.w};
        #pragma unroll
        for (int i = 0; i < 4; ++i)
            #pragma unroll
            for (int j = 0; j < 4; ++j)
                acc[i][j] = fmaf(a[i], b[j], acc[i][j]);
    }

    const int gm0 = mb + ty * 4;              // 4-aligned within one relation
    if (gm0 < Mtotal) {
        const int r = gm0 / MPR, o = gm0 % MPR;
        float4 bv = make_float4(0.f, 0.f, 0.f, 0.f);
        if (bias) bv = make_float4(bias[o], bias[o+1], bias[o+2], bias[o+3]);
        #pragma unroll
        for (int i = 0; i < 4; ++i) {
            int gn = n0 + tx * 4 + i;
            if (gn < N) {
                float4 v = make_float4(acc[i][0] + bv.x, acc[i][1] + bv.y,
                                       acc[i][2] + bv.z, acc[i][3] + bv.w);
                *(float4*)&C[((size_t)r * N + gn) * MPR + o] = v;
            }
        }
    }
}

// ---------------------------------------------------------------------------
// Edge scatter: out[dst[e], :] += hW[etype[e], src[e], :]. One lane per
// feature channel -> 256B (F=64) / 128B (F=32) coalesced gather per edge.
// ---------------------------------------------------------------------------
template<int F>
__global__ __launch_bounds__(256) void edge_scatter(
    const float* __restrict__ hW,
    const int* __restrict__ src, const int* __restrict__ dst,
    const int* __restrict__ et, float* __restrict__ out, int E, int N)
{
    const int t = blockIdx.x * 256 + threadIdx.x;
    const int e = t / F;
    const int lane = t % F;
    if (e >= E) return;
    const int s = src[e];
    const int d = dst[e];
    const int r = et[e];
    const float v = hW[((size_t)r * N + s) * F + lane];
    atomicAdd(&out[(size_t)d * F + lane], v);
}

extern "C" void kernel_launch(void* const* d_in, const int* in_sizes, int n_in,
                              void* d_out, int out_size, void* d_ws, size_t ws_size,
                              hipStream_t stream)
{
    const float* feat = (const float*)d_in[0];
    const int*   src  = (const int*)d_in[1];
    const int*   dst  = (const int*)d_in[2];
    const int*   et   = (const int*)d_in[3];
    const float* W1   = (const float*)d_in[4];
    const float* Ws1  = (const float*)d_in[5];
    const float* b1   = (const float*)d_in[6];
    const float* W2   = (const float*)d_in[7];
    const float* Ws2  = (const float*)d_in[8];
    const float* b2   = (const float*)d_in[9];
    float* out = (float*)d_out;

    const int N = in_sizes[0] / 64;           // 100000
    const int E = in_sizes[1];                // 1600000
    const int R = in_sizes[4] / (64 * 64);    // 8

    float* hW = (float*)d_ws;                 // [R][N][64] then reused [R][N][32]
    float* h1 = hW + (size_t)R * N * 64;      // [N][64]

    const dim3 blk(256);
    const int nblk = (N + 63) / 64;

    // ---- Layer 1 ----
    // hW1[r][n][h] = feat[n] . W1[r][:,h]
    gemm_rel<64><<<dim3(nblk, R), blk, 0, stream>>>(feat, W1, nullptr, hW, N, R * 64, 0);
    // h1[n][h] = feat[n] . Wself1[:,h] + b1[h]   (agg init)
    gemm_rel<64><<<dim3(nblk, 1), blk, 0, stream>>>(feat, Ws1, b1, h1, N, 64, 0);
    // h1[dst] += hW1[etype, src]
    edge_scatter<64><<<dim3((E + 3) / 4), blk, 0, stream>>>(hW, src, dst, et, h1, E, N);

    // ---- Layer 2 ---- (ReLU fused into A-loads)
    // hW2[r][n][o] = relu(h1[n]) . W2[r][:,o]
    gemm_rel<32><<<dim3(nblk, (R * 32 + 63) / 64), blk, 0, stream>>>(h1, W2, nullptr, hW, N, R * 32, 1);
    // out[n][o] = relu(h1[n]) . Wself2[:,o] + b2[o]
    gemm_rel<32><<<dim3(nblk, 1), blk, 0, stream>>>(h1, Ws2, b2, out, N, 32, 1);
    // out[dst] += hW2[etype, src]
    edge_scatter<32><<<dim3((E + 7) / 8), blk, 0, stream>>>(hW, src, dst, et, out, E, N);
}

// Round 2
// 737.034 us; speedup vs baseline: 1.3073x; 1.3073x over previous
//
#include <hip/hip_runtime.h>

// ---------------------------------------------------------------------------
// Tiled GEMM: C[r][n][MPR] = A[n][64] * B[r][64][MPR] (+ bias), optional ReLU
// on A at load. 64 nodes x 64 m-columns per block, 256 threads, 4x4 register
// tile per thread.
// ---------------------------------------------------------------------------
template<int MPR>
__global__ __launch_bounds__(256) void gemm_rel(
    const float* __restrict__ A, const float* __restrict__ B,
    const float* __restrict__ bias, float* __restrict__ C,
    int N, int Mtotal, int relu)
{
    __shared__ float As[64][68];   // [d][n], padded
    __shared__ float Bs[64][64];   // [d][m_local]
    const int tid = threadIdx.x;
    const int n0 = blockIdx.x * 64;
    const int mb = blockIdx.y * 64;

    #pragma unroll
    for (int idx = tid; idx < 4096; idx += 256) {
        int n = idx >> 6, d = idx & 63;
        int gn = n0 + n;
        float v = 0.f;
        if (gn < N) v = A[(size_t)gn * 64 + d];
        if (relu) v = fmaxf(v, 0.f);
        As[d][n] = v;
    }
    #pragma unroll
    for (int idx = tid; idx < 4096; idx += 256) {
        int d = idx >> 6, ml = idx & 63;
        int gm = mb + ml;
        float v = 0.f;
        if (gm < Mtotal) {
            int r = gm / MPR, o = gm % MPR;
            v = B[((size_t)r * 64 + d) * MPR + o];
        }
        Bs[d][ml] = v;
    }
    __syncthreads();

    const int tx = tid & 15, ty = tid >> 4;
    float acc[4][4] = {};
    #pragma unroll 8
    for (int d = 0; d < 64; ++d) {
        float4 a4 = *(const float4*)&As[d][tx * 4];
        float4 b4 = *(const float4*)&Bs[d][ty * 4];
        float a[4] = {a4.x, a4.y, a4.z, a4.w};
        float b[4] = {b4.x, b4.y, b4.z, b4.w};
        #pragma unroll
        for (int i = 0; i < 4; ++i)
            #pragma unroll
            for (int j = 0; j < 4; ++j)
                acc[i][j] = fmaf(a[i], b[j], acc[i][j]);
    }

    const int gm0 = mb + ty * 4;
    if (gm0 < Mtotal) {
        const int r = gm0 / MPR, o = gm0 % MPR;
        float4 bv = make_float4(0.f, 0.f, 0.f, 0.f);
        if (bias) bv = make_float4(bias[o], bias[o+1], bias[o+2], bias[o+3]);
        #pragma unroll
        for (int i = 0; i < 4; ++i) {
            int gn = n0 + tx * 4 + i;
            if (gn < N) {
                float4 v = make_float4(acc[i][0] + bv.x, acc[i][1] + bv.y,
                                       acc[i][2] + bv.z, acc[i][3] + bv.w);
                *(float4*)&C[((size_t)r * N + gn) * MPR + o] = v;
            }
        }
    }
}

// ---------------------------------------------------------------------------
// CSR construction: histogram of dst -> exclusive scan -> scatter edge ids.
// eidx[p] stores (et*N + src), the row index into hW, grouped by dst.
// ---------------------------------------------------------------------------
__global__ __launch_bounds__(256) void zero_int(int* __restrict__ p, int n) {
    int i = blockIdx.x * 256 + threadIdx.x;
    if (i < n) p[i] = 0;
}

__global__ __launch_bounds__(256) void hist_dst(const int* __restrict__ dst,
                                               int* __restrict__ cnt, int E) {
    int e = blockIdx.x * 256 + threadIdx.x;
    if (e < E) atomicAdd(&cnt[dst[e]], 1);
}

// Per-block (1024-element) exclusive scan; block totals to bsums.
__global__ __launch_bounds__(256) void scan1(const int* __restrict__ cnt,
                                             int* __restrict__ excl,
                                             int* __restrict__ bsums, int N) {
    __shared__ int ts[256];
    const int t = threadIdx.x;
    const int base = blockIdx.x * 1024 + t * 4;
    int v[4], s = 0;
    #pragma unroll
    for (int j = 0; j < 4; ++j) {
        v[j] = (base + j < N) ? cnt[base + j] : 0;
        s += v[j];
    }
    ts[t] = s;
    __syncthreads();
    #pragma unroll
    for (int off = 1; off < 256; off <<= 1) {
        int x = (t >= off) ? ts[t - off] : 0;
        __syncthreads();
        ts[t] += x;
        __syncthreads();
    }
    int run = ts[t] - s;   // exclusive prefix of this thread
    #pragma unroll
    for (int j = 0; j < 4; ++j) {
        if (base + j < N) excl[base + j] = run;
        run += v[j];
    }
    if (t == 255) bsums[blockIdx.x] = ts[255];
}

// Single-block exclusive scan of block sums (nb <= 128).
__global__ __launch_bounds__(128) void scan2(int* __restrict__ bsums, int nb) {
    __shared__ int ts[128];
    const int t = threadIdx.x;
    int v = (t < nb) ? bsums[t] : 0;
    ts[t] = v;
    __syncthreads();
    #pragma unroll
    for (int off = 1; off < 128; off <<= 1) {
        int x = (t >= off) ? ts[t - off] : 0;
        __syncthreads();
        ts[t] += x;
        __syncthreads();
    }
    if (t < nb) bsums[t] = ts[t] - v;
}

__global__ __launch_bounds__(256) void scan3(int* __restrict__ row_ptr,
                                             const int* __restrict__ bsums,
                                             int* __restrict__ cursors,
                                             int N, int E) {
    int i = blockIdx.x * 256 + threadIdx.x;
    if (i < N) {
        int v = row_ptr[i] + bsums[i >> 10];
        row_ptr[i] = v;
        cursors[i] = v;
    }
    if (i == 0) row_ptr[N] = E;
}

__global__ __launch_bounds__(256) void scatter_edges(
    const int* __restrict__ src, const int* __restrict__ dst,
    const int* __restrict__ et, int* __restrict__ cursors,
    int* __restrict__ eidx, int E, int N)
{
    int e = blockIdx.x * 256 + threadIdx.x;
    if (e >= E) return;
    int pos = atomicAdd(&cursors[dst[e]], 1);
    eidx[pos] = et[e] * N + src[e];
}

// ---------------------------------------------------------------------------
// Gather-side aggregation (no atomics): F lanes per dst node; loop CSR range,
// accumulate in registers, single += to out.
// ---------------------------------------------------------------------------
template<int F>
__global__ __launch_bounds__(256) void agg_csr(
    const float* __restrict__ hW, const int* __restrict__ row_ptr,
    const int* __restrict__ eidx, float* __restrict__ out, int N)
{
    constexpr int G = 256 / F;
    const int d = blockIdx.x * G + threadIdx.x / F;
    const int lane = threadIdx.x % F;
    if (d >= N) return;
    const int p1 = row_ptr[d + 1];
    int p = row_ptr[d];
    float acc = 0.f;
    for (; p + 1 < p1; p += 2) {
        int i0 = eidx[p], i1 = eidx[p + 1];
        acc += hW[(size_t)i0 * F + lane];
        acc += hW[(size_t)i1 * F + lane];
    }
    if (p < p1) acc += hW[(size_t)eidx[p] * F + lane];
    out[(size_t)d * F + lane] += acc;
}

extern "C" void kernel_launch(void* const* d_in, const int* in_sizes, int n_in,
                              void* d_out, int out_size, void* d_ws, size_t ws_size,
                              hipStream_t stream)
{
    const float* feat = (const float*)d_in[0];
    const int*   src  = (const int*)d_in[1];
    const int*   dst  = (const int*)d_in[2];
    const int*   et   = (const int*)d_in[3];
    const float* W1   = (const float*)d_in[4];
    const float* Ws1  = (const float*)d_in[5];
    const float* b1   = (const float*)d_in[6];
    const float* W2   = (const float*)d_in[7];
    const float* Ws2  = (const float*)d_in[8];
    const float* b2   = (const float*)d_in[9];
    float* out = (float*)d_out;

    const int N = in_sizes[0] / 64;           // 100000
    const int E = in_sizes[1];                // 1600000
    const int R = in_sizes[4] / (64 * 64);    // 8

    // Workspace layout
    float* hW      = (float*)d_ws;                       // [R][N][64] (reused [R][N][32])
    float* h1      = hW + (size_t)R * N * 64;            // [N][64]
    int*   row_ptr = (int*)(h1 + (size_t)N * 64);        // [N+1]
    int*   cnt     = row_ptr + (N + 1);                  // [N] (histogram)
    int*   cursors = cnt + N;                            // [N]
    int*   bsums   = cursors + N;                        // [nblk1024]
    int*   eidx    = bsums + 256;                        // [E]

    const dim3 blk(256);
    const int nblkN   = (N + 255) / 256;
    const int nblkE   = (E + 255) / 256;
    const int nblk64  = (N + 63) / 64;
    const int nblk1024 = (N + 1023) / 1024;   // 98

    // ---- CSR build ----
    zero_int<<<nblkN, blk, 0, stream>>>(cnt, N);
    hist_dst<<<nblkE, blk, 0, stream>>>(dst, cnt, E);
    scan1<<<nblk1024, blk, 0, stream>>>(cnt, row_ptr, bsums, N);
    scan2<<<1, 128, 0, stream>>>(bsums, nblk1024);
    scan3<<<nblkN, blk, 0, stream>>>(row_ptr, bsums, cursors, N, E);
    scatter_edges<<<nblkE, blk, 0, stream>>>(src, dst, et, cursors, eidx, E, N);

    // ---- Layer 1 ----
    gemm_rel<64><<<dim3(nblk64, R), blk, 0, stream>>>(feat, W1, nullptr, hW, N, R * 64, 0);
    gemm_rel<64><<<dim3(nblk64, 1), blk, 0, stream>>>(feat, Ws1, b1, h1, N, 64, 0);
    agg_csr<64><<<dim3((N + 3) / 4), blk, 0, stream>>>(hW, row_ptr, eidx, h1, N);

    // ---- Layer 2 ---- (ReLU fused into A-loads)
    gemm_rel<32><<<dim3(nblk64, (R * 32 + 63) / 64), blk, 0, stream>>>(h1, W2, nullptr, hW, N, R * 32, 1);
    gemm_rel<32><<<dim3(nblk64, 1), blk, 0, stream>>>(h1, Ws2, b2, out, N, 32, 1);
    agg_csr<32><<<dim3((N + 7) / 8), blk, 0, stream>>>(hW, row_ptr, eidx, out, N);
}

// Round 3
// 593.781 us; speedup vs baseline: 1.6227x; 1.2413x over previous
//
#include <hip/hip_runtime.h>
#include <hip/hip_bf16.h>

typedef __attribute__((ext_vector_type(8))) short short8;
typedef __attribute__((ext_vector_type(4))) float f32x4;

__device__ __forceinline__ unsigned short f2bf(float v) {
    __hip_bfloat16 h = __float2bfloat16(v);   // RNE
    return *reinterpret_cast<unsigned short*>(&h);
}
__device__ __forceinline__ float bf2f(unsigned short u) {
    union { unsigned int i; float f; } x;
    x.i = (unsigned int)u << 16;
    return x.f;
}

// ---------------------------------------------------------------------------
// MFMA relation GEMM: C[r][n][H] = bf16(A[n][64]) . bf16(W[r][64][H]) for all
// r in one block (A staged once). 256 thr = 4 waves; wave w computes 16 nodes.
// LDS rows padded to stride 88 (176 B: 16B-aligned, <=2-way bank alias=free).
// ---------------------------------------------------------------------------
template<int H>   // 64 (layer1) or 32 (layer2)
__global__ __launch_bounds__(256) void gemm_rel_mfma(
    const float* __restrict__ A, const float* __restrict__ W,
    unsigned short* __restrict__ C, int N, int R, int relu)
{
    constexpr int AS = 88;
    __shared__ unsigned short As[64 * AS];   // [node][d]
    __shared__ unsigned short Bs[H * AS];    // [h][d]  (W transposed)
    const int tid = threadIdx.x;
    const int n0 = blockIdx.x * 64;

    // Stage A tile fp32 -> bf16 (optional ReLU), 4 float4 loads per thread.
    #pragma unroll
    for (int i = 0; i < 4; ++i) {
        int lin = tid + i * 256;            // 1024 float4 slots
        int n = lin >> 4;
        int d4 = (lin & 15) * 4;
        int gn = n0 + n;
        float4 v = make_float4(0.f, 0.f, 0.f, 0.f);
        if (gn < N) v = *(const float4*)&A[(size_t)gn * 64 + d4];
        if (relu) {
            v.x = fmaxf(v.x, 0.f); v.y = fmaxf(v.y, 0.f);
            v.z = fmaxf(v.z, 0.f); v.w = fmaxf(v.w, 0.f);
        }
        ushort4 u;
        u.x = f2bf(v.x); u.y = f2bf(v.y); u.z = f2bf(v.z); u.w = f2bf(v.w);
        *(ushort4*)&As[n * AS + d4] = u;
    }

    const int w = tid >> 6, lane = tid & 63;
    const int m = lane & 15, quad = lane >> 4;

    __syncthreads();

    // Preload A fragments (reused across all relations).
    short8 afrag[2];
    afrag[0] = *(const short8*)&As[(w * 16 + m) * AS + 0 * 32 + quad * 8];
    afrag[1] = *(const short8*)&As[(w * 16 + m) * AS + 1 * 32 + quad * 8];

    constexpr int NT = H / 16;
    for (int r = 0; r < R; ++r) {
        __syncthreads();   // previous iteration's Bs reads done
        #pragma unroll
        for (int i = 0; i < (64 * H) / 256; ++i) {
            int lin = tid + i * 256;
            int d = lin / H;
            int h = lin % H;
            Bs[h * AS + d] = f2bf(W[((size_t)r * 64 + d) * H + h]);
        }
        __syncthreads();

        f32x4 acc[NT];
        #pragma unroll
        for (int nt = 0; nt < NT; ++nt) {
            acc[nt] = (f32x4){0.f, 0.f, 0.f, 0.f};
            #pragma unroll
            for (int kc = 0; kc < 2; ++kc) {
                short8 bfrag = *(const short8*)&Bs[(nt * 16 + m) * AS + kc * 32 + quad * 8];
                acc[nt] = __builtin_amdgcn_mfma_f32_16x16x32_bf16(afrag[kc], bfrag, acc[nt], 0, 0, 0);
            }
        }
        // C/D layout: col = lane&15, row = quad*4 + i.
        #pragma unroll
        for (int nt = 0; nt < NT; ++nt) {
            int col = nt * 16 + m;
            #pragma unroll
            for (int i = 0; i < 4; ++i) {
                int node = n0 + w * 16 + quad * 4 + i;
                if (node < N)
                    C[((size_t)r * N + node) * H + col] = f2bf(acc[nt][i]);
            }
        }
    }
}

// ---------------------------------------------------------------------------
// fp32 tiled GEMM for the small self-loop terms (C = A.B + bias, opt ReLU(A)).
// ---------------------------------------------------------------------------
template<int MPR>
__global__ __launch_bounds__(256) void gemm_rel(
    const float* __restrict__ A, const float* __restrict__ B,
    const float* __restrict__ bias, float* __restrict__ C,
    int N, int Mtotal, int relu)
{
    __shared__ float As[64][68];
    __shared__ float Bs[64][64];
    const int tid = threadIdx.x;
    const int n0 = blockIdx.x * 64;
    const int mb = blockIdx.y * 64;

    #pragma unroll
    for (int idx = tid; idx < 4096; idx += 256) {
        int n = idx >> 6, d = idx & 63;
        int gn = n0 + n;
        float v = 0.f;
        if (gn < N) v = A[(size_t)gn * 64 + d];
        if (relu) v = fmaxf(v, 0.f);
        As[d][n] = v;
    }
    #pragma unroll
    for (int idx = tid; idx < 4096; idx += 256) {
        int d = idx >> 6, ml = idx & 63;
        int gm = mb + ml;
        float v = 0.f;
        if (gm < Mtotal) {
            int r = gm / MPR, o = gm % MPR;
            v = B[((size_t)r * 64 + d) * MPR + o];
        }
        Bs[d][ml] = v;
    }
    __syncthreads();

    const int tx = tid & 15, ty = tid >> 4;
    float acc[4][4] = {};
    #pragma unroll 8
    for (int d = 0; d < 64; ++d) {
        float4 a4 = *(const float4*)&As[d][tx * 4];
        float4 b4 = *(const float4*)&Bs[d][ty * 4];
        float a[4] = {a4.x, a4.y, a4.z, a4.w};
        float b[4] = {b4.x, b4.y, b4.z, b4.w};
        #pragma unroll
        for (int i = 0; i < 4; ++i)
            #pragma unroll
            for (int j = 0; j < 4; ++j)
                acc[i][j] = fmaf(a[i], b[j], acc[i][j]);
    }

    const int gm0 = mb + ty * 4;
    if (gm0 < Mtotal) {
        const int r = gm0 / MPR, o = gm0 % MPR;
        float4 bv = make_float4(0.f, 0.f, 0.f, 0.f);
        if (bias) bv = make_float4(bias[o], bias[o+1], bias[o+2], bias[o+3]);
        #pragma unroll
        for (int i = 0; i < 4; ++i) {
            int gn = n0 + tx * 4 + i;
            if (gn < N) {
                float4 v = make_float4(acc[i][0] + bv.x, acc[i][1] + bv.y,
                                       acc[i][2] + bv.z, acc[i][3] + bv.w);
                *(float4*)&C[((size_t)r * N + gn) * MPR + o] = v;
            }
        }
    }
}

// ---------------------------------------------------------------------------
// CSR construction: histogram of dst -> exclusive scan -> scatter edge ids.
// ---------------------------------------------------------------------------
__global__ __launch_bounds__(256) void zero_int(int* __restrict__ p, int n) {
    int i = blockIdx.x * 256 + threadIdx.x;
    if (i < n) p[i] = 0;
}

__global__ __launch_bounds__(256) void hist_dst(const int* __restrict__ dst,
                                               int* __restrict__ cnt, int E) {
    int e = blockIdx.x * 256 + threadIdx.x;
    if (e < E) atomicAdd(&cnt[dst[e]], 1);
}

__global__ __launch_bounds__(256) void scan1(const int* __restrict__ cnt,
                                             int* __restrict__ excl,
                                             int* __restrict__ bsums, int N) {
    __shared__ int ts[256];
    const int t = threadIdx.x;
    const int base = blockIdx.x * 1024 + t * 4;
    int v[4], s = 0;
    #pragma unroll
    for (int j = 0; j < 4; ++j) {
        v[j] = (base + j < N) ? cnt[base + j] : 0;
        s += v[j];
    }
    ts[t] = s;
    __syncthreads();
    #pragma unroll
    for (int off = 1; off < 256; off <<= 1) {
        int x = (t >= off) ? ts[t - off] : 0;
        __syncthreads();
        ts[t] += x;
        __syncthreads();
    }
    int run = ts[t] - s;
    #pragma unroll
    for (int j = 0; j < 4; ++j) {
        if (base + j < N) excl[base + j] = run;
        run += v[j];
    }
    if (t == 255) bsums[blockIdx.x] = ts[255];
}

__global__ __launch_bounds__(128) void scan2(int* __restrict__ bsums, int nb) {
    __shared__ int ts[128];
    const int t = threadIdx.x;
    int v = (t < nb) ? bsums[t] : 0;
    ts[t] = v;
    __syncthreads();
    #pragma unroll
    for (int off = 1; off < 128; off <<= 1) {
        int x = (t >= off) ? ts[t - off] : 0;
        __syncthreads();
        ts[t] += x;
        __syncthreads();
    }
    if (t < nb) bsums[t] = ts[t] - v;
}

__global__ __launch_bounds__(256) void scan3(int* __restrict__ row_ptr,
                                             const int* __restrict__ bsums,
                                             int* __restrict__ cursors,
                                             int N, int E) {
    int i = blockIdx.x * 256 + threadIdx.x;
    if (i < N) {
        int v = row_ptr[i] + bsums[i >> 10];
        row_ptr[i] = v;
        cursors[i] = v;
    }
    if (i == 0) row_ptr[N] = E;
}

__global__ __launch_bounds__(256) void scatter_edges(
    const int* __restrict__ src, const int* __restrict__ dst,
    const int* __restrict__ et, int* __restrict__ cursors,
    int* __restrict__ eidx, int E, int N)
{
    int e = blockIdx.x * 256 + threadIdx.x;
    if (e >= E) return;
    int pos = atomicAdd(&cursors[dst[e]], 1);
    eidx[pos] = et[e] * N + src[e];
}

// ---------------------------------------------------------------------------
// Gather-side aggregation over bf16 hW (no atomics), fp32 accumulate.
// ---------------------------------------------------------------------------
template<int F>
__global__ __launch_bounds__(256) void agg_csr(
    const unsigned short* __restrict__ hW, const int* __restrict__ row_ptr,
    const int* __restrict__ eidx, float* __restrict__ out, int N)
{
    constexpr int G = 256 / F;
    const int d = blockIdx.x * G + threadIdx.x / F;
    const int lane = threadIdx.x % F;
    if (d >= N) return;
    const int p1 = row_ptr[d + 1];
    int p = row_ptr[d];
    float acc = 0.f;
    for (; p + 1 < p1; p += 2) {
        int i0 = eidx[p], i1 = eidx[p + 1];
        acc += bf2f(hW[(size_t)i0 * F + lane]);
        acc += bf2f(hW[(size_t)i1 * F + lane]);
    }
    if (p < p1) acc += bf2f(hW[(size_t)eidx[p] * F + lane]);
    out[(size_t)d * F + lane] += acc;
}

extern "C" void kernel_launch(void* const* d_in, const int* in_sizes, int n_in,
                              void* d_out, int out_size, void* d_ws, size_t ws_size,
                              hipStream_t stream)
{
    const float* feat = (const float*)d_in[0];
    const int*   src  = (const int*)d_in[1];
    const int*   dst  = (const int*)d_in[2];
    const int*   et   = (const int*)d_in[3];
    const float* W1   = (const float*)d_in[4];
    const float* Ws1  = (const float*)d_in[5];
    const float* b1   = (const float*)d_in[6];
    const float* W2   = (const float*)d_in[7];
    const float* Ws2  = (const float*)d_in[8];
    const float* b2   = (const float*)d_in[9];
    float* out = (float*)d_out;

    const int N = in_sizes[0] / 64;           // 100000
    const int E = in_sizes[1];                // 1600000
    const int R = in_sizes[4] / (64 * 64);    // 8

    // Workspace layout
    unsigned short* hW = (unsigned short*)d_ws;          // [R][N][64] bf16 (reused [R][N][32])
    float* h1      = (float*)(hW + (size_t)R * N * 64);  // [N][64] fp32
    int*   row_ptr = (int*)(h1 + (size_t)N * 64);        // [N+1]
    int*   cnt     = row_ptr + (N + 1);                  // [N]
    int*   cursors = cnt + N;                            // [N]
    int*   bsums   = cursors + N;                        // [nblk1024]
    int*   eidx    = bsums + 256;                        // [E]

    const dim3 blk(256);
    const int nblkN    = (N + 255) / 256;
    const int nblkE    = (E + 255) / 256;
    const int nblk64   = (N + 63) / 64;
    const int nblk1024 = (N + 1023) / 1024;

    // ---- CSR build ----
    zero_int<<<nblkN, blk, 0, stream>>>(cnt, N);
    hist_dst<<<nblkE, blk, 0, stream>>>(dst, cnt, E);
    scan1<<<nblk1024, blk, 0, stream>>>(cnt, row_ptr, bsums, N);
    scan2<<<1, 128, 0, stream>>>(bsums, nblk1024);
    scan3<<<nblkN, blk, 0, stream>>>(row_ptr, bsums, cursors, N, E);
    scatter_edges<<<nblkE, blk, 0, stream>>>(src, dst, et, cursors, eidx, E, N);

    // ---- Layer 1 ----
    gemm_rel_mfma<64><<<dim3(nblk64), blk, 0, stream>>>(feat, W1, hW, N, R, 0);
    gemm_rel<64><<<dim3(nblk64, 1), blk, 0, stream>>>(feat, Ws1, b1, h1, N, 64, 0);
    agg_csr<64><<<dim3((N + 3) / 4), blk, 0, stream>>>(hW, row_ptr, eidx, h1, N);

    // ---- Layer 2 ---- (ReLU fused into A staging)
    gemm_rel_mfma<32><<<dim3(nblk64), blk, 0, stream>>>(h1, W2, hW, N, R, 1);
    gemm_rel<32><<<dim3(nblk64, 1), blk, 0, stream>>>(h1, Ws2, b2, out, N, 32, 1);
    agg_csr<32><<<dim3((N + 7) / 8), blk, 0, stream>>>(hW, row_ptr, eidx, out, N);
}